// Round 8
// baseline (65.038 us; speedup 1.0000x reference)
//
#include <hip/hip_runtime.h>
#include <hip/hip_bf16.h>

// ---------------------------------------------------------------------------
// Triplet loss via ONE 4096^2 sq-distance GEMM (transpose symmetry):
//   G[i,j] = ||i_f[i]||^2 + ||v_f[j]+eps||^2 - 2 i_f[i].(v_f[j]+eps)
//   loss_i: per row i (anchor i_f[i]); loss_v: per col j (anchor v_f[j]).
//   (dir-2 sq differs by 4*eps*(S_i - S_v) ~ 2.6e-4 on sq ~ 2048 -> noise)
// 16-wave (1024-thread) 256^2 tile, 4 waves/SIMD for TLP across barriers.
// Waves 4Mx4N, 64x64 output each. 4 phases per K-tile of 64:
//   ph0 (mh0,nh0): 8 ds_read; stage Bh0(t+1)->o
//   ph1 (mh0,nh1): 4 ds_read; stage Bh1(t+1)->o
//   ph2 (mh1,nh0): 4 ds_read
//   ph3 (mh1,nh1): 0 ds_read; stage Ah0,Ah1(t+2)->c ; vmcnt(2) (never 0)
// A[c] is fully read only after ph2 (wave rows span both halves), hence the
// A(t+2) skew; B(t+1) gets 2-phase landing slack.
// ---------------------------------------------------------------------------

#define MDIM 4096
#define KDIM 1024
#define NT   16      // K-tiles of 64

typedef __attribute__((ext_vector_type(4))) float  f32x4;
typedef __attribute__((ext_vector_type(8))) short  bf16x8;

__device__ __forceinline__ void gload16(const void* g, void* l) {
  __builtin_amdgcn_global_load_lds(
      (const __attribute__((address_space(1))) void*)g,
      (__attribute__((address_space(3))) void*)l,
      16, 0, 0);
}

__device__ __forceinline__ unsigned short f2bf(float x) {
  unsigned int u = __float_as_uint(x);
  unsigned int r = (u + 0x7FFFu + ((u >> 16) & 1u)) >> 16;  // RNE
  return (unsigned short)r;
}

#define BAR() do { asm volatile("" ::: "memory"); \
                   __builtin_amdgcn_s_barrier();  \
                   asm volatile("" ::: "memory"); } while (0)

// --- prep: wave-per-row f32 -> bf16 + row norms; fused init of reduce bufs --
__global__ __launch_bounds__(256) void prep_kernel(
    const float* __restrict__ vf, const float* __restrict__ iff,
    unsigned short* __restrict__ vb, unsigned short* __restrict__ ib,
    float* __restrict__ ni, float* __restrict__ nvp,
    int* __restrict__ same_sq, int* __restrict__ diff_sq,
    float* __restrict__ out) {
  const int wid = blockIdx.x * 4 + (threadIdx.x >> 6);  // 0..8191, wave = row
  const int lane = threadIdx.x & 63;
  const int mat = wid >> 12;              // 0 = v_f, 1 = i_f
  const int row = wid & 4095;
  const float* X = mat ? iff : vf;
  unsigned short* Xb = mat ? ib : vb;

  const float4* xr4 = (const float4*)(X + (size_t)row * KDIM);
  ushort4* xb4 = (ushort4*)(Xb + (size_t)row * KDIM);

  float4 v = xr4[lane];
  ushort4 o;
  o.x = f2bf(v.x); o.y = f2bf(v.y); o.z = f2bf(v.z); o.w = f2bf(v.w);
  xb4[lane] = o;

  float s;
  if (mat) {  // i_f: plain norm
    s = v.x * v.x + v.y * v.y + v.z * v.z + v.w * v.w;
  } else {    // v_f: norm of (x + eps)
    float ex = v.x + 1e-6f, ey = v.y + 1e-6f, ez = v.z + 1e-6f, ew = v.w + 1e-6f;
    s = ex * ex + ey * ey + ez * ez + ew * ew;
  }
  for (int off = 32; off; off >>= 1) s += __shfl_down(s, off);
  if (lane == 0) {
    if (mat) ni[row] = s; else nvp[row] = s;
  }

  // fused init (first 32 blocks cover the 8192-entry reduce buffers)
  const int gi = blockIdx.x * 256 + threadIdx.x;
  if (gi < 2 * MDIM) {
    same_sq[gi] = 0;             // sq >= 0: 0 is max-identity
    diff_sq[gi] = 0x7F800000;    // +inf
  }
  if (gi == 0) out[0] = 0.0f;
}

// --- fused 256x256 GEMM (16 waves) + distance + masked row AND col max/min -
// A = i_f (rows), B = v_f (+eps norms) (cols).
__global__ __launch_bounds__(1024, 4) void tri_gemm(
    const unsigned short* __restrict__ vb, const unsigned short* __restrict__ ib,
    const float* __restrict__ ni, const float* __restrict__ nvp,
    const int* __restrict__ y,
    int* __restrict__ same_sq, int* __restrict__ diff_sq) {
  // K-tile buffer: [256 rows][64 k] bf16, row = 128 B, 8 chunks of 16 B.
  // XOR swizzle: data for (row, chunk) lives at (row, chunk ^ (row&7)).
  // global_load_lds dest stays linear; source address is pre-swizzled.
  __shared__ unsigned short Abuf[2][256][64];   // 64 KiB
  __shared__ unsigned short Bbuf[2][256][64];   // 64 KiB
  __shared__ int   yrow[256], ycol[256];
  __shared__ float nAr[256], nBc[256];

  const unsigned short* Amat = ib;
  const unsigned short* Bmat = vb;

  const int row0 = blockIdx.y * 256;
  const int col0 = blockIdx.x * 256;

  const int t = threadIdx.x;
  const int w = t >> 6, lane = t & 63;
  const int lr = lane & 15, lg = lane >> 4;
  const int wr = w >> 2, wc = w & 3;            // 4 x 4 waves -> 64 x 64 tile

  // stage one half-tile (128 rows x 64 k = 16 KB) = 1 gload16 per thread
  auto stage = [&](const unsigned short* __restrict__ X, int tile0,
                   unsigned short (&buf)[256][64], int h, int k0s) {
    const int row = h * 128 + (t >> 3);
    const int chunk = t & 7;
    const unsigned short* src =
        X + (size_t)(tile0 + row) * KDIM + k0s + ((chunk ^ (row & 7)) << 3);
    gload16(src, &buf[h * 128 + (w << 3)][0]);   // wave-uniform base
  };
  auto ldA = [&](int c, int mh, int m, int ks) -> bf16x8 {
    const int row = wr * 64 + mh * 32 + m * 16 + lr;
    const int chunk = ((ks << 2) | lg) ^ (row & 7);
    return *(const bf16x8*)&Abuf[c][row][chunk << 3];
  };
  auto ldB = [&](int c, int nh, int n, int ks) -> bf16x8 {
    const int col = wc * 64 + nh * 32 + n * 16 + lr;
    const int chunk = ((ks << 2) | lg) ^ (col & 7);
    return *(const bf16x8*)&Bbuf[c][col][chunk << 3];
  };

  // ---- prologue: tile 0 fully + tile 1 A both halves; labels/norms ----
  stage(Amat, row0, Abuf[0], 0, 0);
  stage(Amat, row0, Abuf[0], 1, 0);
  stage(Bmat, col0, Bbuf[0], 0, 0);
  stage(Bmat, col0, Bbuf[0], 1, 0);
  stage(Amat, row0, Abuf[1], 0, 64);
  stage(Amat, row0, Abuf[1], 1, 64);
  if (t < 256) {
    yrow[t] = y[row0 + t];
    nAr[t] = ni[row0 + t];
  } else if (t < 512) {
    const int c = t - 256;
    ycol[c] = y[col0 + c];
    nBc[c] = nvp[col0 + c];
  }
  // drain tile 0 (ph0 reads A rows of BOTH halves + B both halves);
  // keep tile-1 A (2 loads) in flight.
  asm volatile("s_waitcnt vmcnt(2) lgkmcnt(0)" ::: "memory");
  BAR();

  f32x4 acc[4][4] = {};
  bf16x8 aF[2][2], bF0[2][2], bF1[2][2];

// One K-tile = 4 phases. C: buffer of tile t (literal 0/1); K1: k-offset of
// tile t+1 (B stages); K2: k-offset of tile t+2 (A stages into buf C).
#define DO_TILE(C, K1, K2)                                                     \
  do {                                                                         \
    /* ph0 (mh0,nh0): read aF(mh=0) + bF0; stage B-h0(t+1) */                  \
    _Pragma("unroll") for (int m = 0; m < 2; ++m)                              \
      _Pragma("unroll") for (int ks = 0; ks < 2; ++ks)                         \
        aF[m][ks] = ldA(C, 0, m, ks);                                          \
    _Pragma("unroll") for (int n = 0; n < 2; ++n)                              \
      _Pragma("unroll") for (int ks = 0; ks < 2; ++ks)                         \
        bF0[n][ks] = ldB(C, 0, n, ks);                                         \
    stage(Bmat, col0, Bbuf[1 - (C)], 0, (K1));                                 \
    BAR();                                                                     \
    __builtin_amdgcn_s_setprio(1);                                             \
    _Pragma("unroll") for (int m = 0; m < 2; ++m)                              \
      _Pragma("unroll") for (int n = 0; n < 2; ++n)                            \
        _Pragma("unroll") for (int ks = 0; ks < 2; ++ks)                       \
          acc[m][n] = __builtin_amdgcn_mfma_f32_16x16x32_bf16(                 \
              aF[m][ks], bF0[n][ks], acc[m][n], 0, 0, 0);                      \
    __builtin_amdgcn_s_setprio(0);                                             \
    BAR();                                                                     \
    /* ph1 (mh0,nh1): read bF1; stage B-h1(t+1) */                             \
    _Pragma("unroll") for (int n = 0; n < 2; ++n)                              \
      _Pragma("unroll") for (int ks = 0; ks < 2; ++ks)                         \
        bF1[n][ks] = ldB(C, 1, n, ks);                                         \
    stage(Bmat, col0, Bbuf[1 - (C)], 1, (K1));                                 \
    BAR();                                                                     \
    __builtin_amdgcn_s_setprio(1);                                             \
    _Pragma("unroll") for (int m = 0; m < 2; ++m)                              \
      _Pragma("unroll") for (int n = 0; n < 2; ++n)                            \
        _Pragma("unroll") for (int ks = 0; ks < 2; ++ks)                       \
          acc[m][2 + n] = __builtin_amdgcn_mfma_f32_16x16x32_bf16(             \
              aF[m][ks], bF1[n][ks], acc[m][2 + n], 0, 0, 0);                  \
    __builtin_amdgcn_s_setprio(0);                                             \
    BAR();                                                                     \
    /* ph2 (mh1,nh0): read aF(mh=1) */                                         \
    _Pragma("unroll") for (int m = 0; m < 2; ++m)                              \
      _Pragma("unroll") for (int ks = 0; ks < 2; ++ks)                         \
        aF[m][ks] = ldA(C, 1, m, ks);                                          \
    BAR();                                                                     \
    __builtin_amdgcn_s_setprio(1);                                             \
    _Pragma("unroll") for (int m = 0; m < 2; ++m)                              \
      _Pragma("unroll") for (int n = 0; n < 2; ++n)                            \
        _Pragma("unroll") for (int ks = 0; ks < 2; ++ks)                       \
          acc[2 + m][n] = __builtin_amdgcn_mfma_f32_16x16x32_bf16(             \
              aF[m][ks], bF0[n][ks], acc[2 + m][n], 0, 0, 0);                  \
    __builtin_amdgcn_s_setprio(0);                                             \
    BAR();                                                                     \
    /* ph3 (mh1,nh1): stage A-h0,A-h1(t+2) into buf C (A[C] read-done at */    \
    /* ph2's barrier); counted wait keeps those 2 loads in flight */           \
    stage(Amat, row0, Abuf[C], 0, (K2));                                       \
    stage(Amat, row0, Abuf[C], 1, (K2));                                       \
    BAR();                                                                     \
    __builtin_amdgcn_s_setprio(1);                                             \
    _Pragma("unroll") for (int m = 0; m < 2; ++m)                              \
      _Pragma("unroll") for (int n = 0; n < 2; ++n)                            \
        _Pragma("unroll") for (int ks = 0; ks < 2; ++ks)                       \
          acc[2 + m][2 + n] = __builtin_amdgcn_mfma_f32_16x16x32_bf16(         \
              aF[m][ks], bF1[n][ks], acc[2 + m][2 + n], 0, 0, 0);              \
    __builtin_amdgcn_s_setprio(0);                                             \
    asm volatile("s_waitcnt vmcnt(2)" ::: "memory");                           \
    BAR();                                                                     \
  } while (0)

  for (int kt = 0; kt < NT; kt += 2) {
    const int ka = ((kt + 1) & (NT - 1)) * 64;
    const int kb = ((kt + 2) & (NT - 1)) * 64;
    const int kc = ((kt + 3) & (NT - 1)) * 64;
    DO_TILE(0, ka, kb);   // even tile lives in buf 0
    DO_TILE(1, kb, kc);   // odd tile lives in buf 1
  }
#undef DO_TILE
  asm volatile("s_waitcnt vmcnt(0)" ::: "memory");

  // ---- epilogue: sq + mask; row-reduce -> loss_i, col-reduce -> loss_v ----
  const int rbase0 = row0;          // dir0: anchors i_f, indexed by row
  const int rbase1 = MDIM + col0;   // dir1: anchors v_f, indexed by col
  const float INF = __int_as_float(0x7F800000);

  float cs[4], cd[4];               // col partials per N (this lane's 16 rows)
#pragma unroll
  for (int N = 0; N < 4; ++N) { cs[N] = 0.0f; cd[N] = INF; }

#pragma unroll
  for (int M = 0; M < 4; ++M) {
#pragma unroll
    for (int r = 0; r < 4; ++r) {
      const int row_loc = wr * 64 + M * 16 + lg * 4 + r;
      const float na = nAr[row_loc];
      const int yl = yrow[row_loc];
      float smax = 0.0f;
      float dmin = INF;
#pragma unroll
      for (int N = 0; N < 4; ++N) {
        const int col_loc = wc * 64 + N * 16 + lr;
        const float sq = fmaxf(na + nBc[col_loc] - 2.0f * acc[M][N][r], 0.0f);
        if (ycol[col_loc] == yl) {
          smax = fmaxf(smax, sq);
          cs[N] = fmaxf(cs[N], sq);
        } else {
          dmin = fminf(dmin, sq);
          cd[N] = fminf(cd[N], sq);
        }
      }
#pragma unroll
      for (int off = 1; off < 16; off <<= 1) {
        smax = fmaxf(smax, __shfl_xor(smax, off));
        dmin = fminf(dmin, __shfl_xor(dmin, off));
      }
      if (lr == 0) {
        // nonneg floats: int compare == float compare -> order-independent
        atomicMax(&same_sq[rbase0 + row_loc], __float_as_int(smax));
        atomicMin(&diff_sq[rbase0 + row_loc], __float_as_int(dmin));
      }
    }
  }
  // col reduce across lg groups (lanes lane^16, lane^32)
#pragma unroll
  for (int N = 0; N < 4; ++N) {
    float s = cs[N], d = cd[N];
    s = fmaxf(s, __shfl_xor(s, 16)); d = fminf(d, __shfl_xor(d, 16));
    s = fmaxf(s, __shfl_xor(s, 32)); d = fminf(d, __shfl_xor(d, 32));
    if (lane < 16) {
      const int col_loc = wc * 64 + N * 16 + lr;
      atomicMax(&same_sq[rbase1 + col_loc], __float_as_int(s));
      atomicMin(&diff_sq[rbase1 + col_loc], __float_as_int(d));
    }
  }
}

// --- finalize: sqrt, relu, sum ---------------------------------------------
__global__ __launch_bounds__(256) void finalize_kernel(
    const int* __restrict__ same_sq, const int* __restrict__ diff_sq,
    float* __restrict__ out) {
  const int i = blockIdx.x * 256 + threadIdx.x;  // 8192 total
  const float sm = sqrtf(__int_as_float(same_sq[i]));
  const float dm = sqrtf(__int_as_float(diff_sq[i]));  // +inf if no diff label
  float l = fmaxf(sm - dm + 1.2f, 0.0f);
  for (int off = 32; off; off >>= 1) l += __shfl_down(l, off);
  __shared__ float part[4];
  const int w = threadIdx.x >> 6, lane = threadIdx.x & 63;
  if (lane == 0) part[w] = l;
  __syncthreads();
  if (threadIdx.x == 0) atomicAdd(out, part[0] + part[1] + part[2] + part[3]);
}

extern "C" void kernel_launch(void* const* d_in, const int* in_sizes, int n_in,
                              void* d_out, int out_size, void* d_ws, size_t ws_size,
                              hipStream_t stream) {
  const float* vf = (const float*)d_in[0];
  const float* iff = (const float*)d_in[1];
  const int* y = (const int*)d_in[2];
  float* out = (float*)d_out;

  char* ws = (char*)d_ws;
  unsigned short* vb = (unsigned short*)ws;                       // 8 MB
  unsigned short* ib = (unsigned short*)(ws + (8u << 20));        // 8 MB
  float* nv  = (float*)(ws + (16u << 20));
  float* ni  = nv + 4096;
  float* nvp = nv + 2 * 4096;
  int* same_sq = (int*)(nv + 4 * 4096);                           // [2][4096]
  int* diff_sq = same_sq + 2 * 4096;                              // [2][4096]

  prep_kernel<<<2048, 256, 0, stream>>>(vf, iff, vb, ib, ni, nvp,
                                        same_sq, diff_sq, out);
  tri_gemm<<<dim3(16, 16), 1024, 0, stream>>>(vb, ib, ni, nvp, y,
                                              same_sq, diff_sq);
  finalize_kernel<<<32, 256, 0, stream>>>(same_sq, diff_sq, out);
}